// Round 1
// baseline (522.738 us; speedup 1.0000x reference)
//
#include <hip/hip_runtime.h>
#include <stdint.h>

#define HW 16384
#define CCH 256
#define GROUP_ELEMS 524288   // 32 ch * 16384 px
#define BK 64
#define LDSP 72              // 64 + 8 bf16 pad -> 144B row stride (16B aligned, 2-way banks)

typedef __attribute__((ext_vector_type(8))) short bfrag8;   // 8 bf16 for MFMA A/B
typedef __attribute__((ext_vector_type(8))) unsigned short us8;
typedef __attribute__((ext_vector_type(4))) float facc4;

static __device__ __forceinline__ unsigned short f2b(float f) {
  union { float f; unsigned int u; } x; x.f = f;
  unsigned int r = x.u + 0x7FFFu + ((x.u >> 16) & 1u);
  return (unsigned short)(r >> 16);
}
static __device__ __forceinline__ float b2f(unsigned short h) {
  union { float f; unsigned int u; } x; x.u = ((unsigned int)h) << 16;
  return x.f;
}

// ---------------- GroupNorm stats ----------------
__global__ void k_red(const float* __restrict__ x, float* __restrict__ red) {
  int gg = blockIdx.x >> 3, sp = blockIdx.x & 7;   // 64 groups x 8 splits
  const float4* p = (const float4*)(x + (size_t)gg * GROUP_ELEMS + (size_t)sp * 65536);
  float s = 0.f, ss = 0.f;
  for (int i = 0; i < 64; ++i) {
    float4 v = p[i * 256 + threadIdx.x];
    s  += v.x + v.y + v.z + v.w;
    ss += v.x*v.x + v.y*v.y + v.z*v.z + v.w*v.w;
  }
  for (int off = 32; off; off >>= 1) { s += __shfl_xor(s, off); ss += __shfl_xor(ss, off); }
  __shared__ float ls[4], lss[4];
  int w = threadIdx.x >> 6;
  if ((threadIdx.x & 63) == 0) { ls[w] = s; lss[w] = ss; }
  __syncthreads();
  if (threadIdx.x == 0) {
    float S = ls[0]+ls[1]+ls[2]+ls[3], SS = lss[0]+lss[1]+lss[2]+lss[3];
    atomicAdd(&red[gg*2], S); atomicAdd(&red[gg*2+1], SS);
  }
}

__global__ void k_fin(const float* __restrict__ red, float* __restrict__ stats) {
  int g = threadIdx.x;   // 64 groups
  float s = red[g*2], ss = red[g*2+1];
  float mean = s / (float)GROUP_ELEMS;
  float var = ss / (float)GROUP_ELEMS - mean*mean;   // biased, matches jnp.var
  stats[g*2] = mean;
  stats[g*2+1] = rsqrtf(var + 1e-5f);
}

// ---------------- weight cast fp32 -> bf16 ----------------
__global__ void k_cast(const float* __restrict__ wq, const float* __restrict__ wp,
                       unsigned short* __restrict__ wqb, unsigned short* __restrict__ wpb) {
  int i = blockIdx.x * 256 + threadIdx.x;   // grid 1024 covers 196608 + 65536
  if (i < 768*256) wqb[i] = f2b(wq[i]);
  else             wpb[i - 768*256] = f2b(wp[i - 768*256]);
}

// ---------------- norm + transpose: x[v][c][p] fp32 -> xnt[v][p][c] bf16 ----------------
__global__ void k_norm_t(const float* __restrict__ xp, const float* __restrict__ stats,
                         const float* __restrict__ gamma, const float* __restrict__ beta,
                         unsigned short* __restrict__ xnt, int pair) {
  __shared__ float tile[64][65];
  int bx = blockIdx.x;
  int v = bx >> 10;                  // 2 views x 256 p-tiles x 4 c-tiles = 2048 blocks
  int rem = bx & 1023;
  int p0 = (rem >> 2) * 64, c0 = (rem & 3) * 64;
  int bv = pair * 2 + v;
  int t = threadIdx.x;
  int p_off = t & 63, c4 = t >> 6;
  const float* xsrc = xp + (size_t)v * CCH * HW;
  for (int cc = 0; cc < 16; ++cc) {
    int c_loc = c4 * 16 + cc;
    int c = c0 + c_loc;
    float val = xsrc[(size_t)c * HW + p0 + p_off];
    int g = bv * 8 + (c >> 5);
    float xn = (val - stats[g*2]) * stats[g*2+1] * gamma[c] + beta[c];
    tile[p_off][c_loc] = xn;
  }
  __syncthreads();
  unsigned short* dst = xnt + (size_t)v * HW * CCH;
  for (int it = 0; it < 8; ++it) {
    int u = it * 256 + t;            // 2048 packed-pair writes
    int p = u >> 5, c2 = u & 31;
    unsigned int pk = (unsigned int)f2b(tile[p][c2*2]) | ((unsigned int)f2b(tile[p][c2*2+1]) << 16);
    *(unsigned int*)(dst + (size_t)(p0 + p) * CCH + c0 + c2*2) = pk;
  }
}

// ---------------- QKV GEMM: D[p][o] = xnt[p][k] . wq[o][k] + bq[o] -> qkvt bf16 ----------------
__global__ __launch_bounds__(256, 2) void k_gemm_qkv(
    const unsigned short* __restrict__ A,   // xnt [32768][256]
    const unsigned short* __restrict__ B,   // wqb [768][256]
    const float* __restrict__ bias,         // [768]
    unsigned short* __restrict__ Cout) {    // qkvt [32768][768]
  __shared__ unsigned short As[128][LDSP];
  __shared__ unsigned short Bs[128][LDSP];
  int row0 = blockIdx.x * 128, col0 = blockIdx.y * 128;
  int t = threadIdx.x;
  int w = t >> 6, lane = t & 63;
  int wm = w & 1, wn = w >> 1;
  int lm = lane & 15, q = lane >> 4;
  facc4 acc[4][4] = {};
  for (int kc = 0; kc < 4; ++kc) {
    for (int i = 0; i < 4; ++i) {
      int flat = i * 256 + t;
      int r = flat >> 3, g = flat & 7;
      *(us8*)(&As[r][g*8]) = *(const us8*)(A + (size_t)(row0 + r)*256 + kc*BK + g*8);
      *(us8*)(&Bs[r][g*8]) = *(const us8*)(B + (size_t)(col0 + r)*256 + kc*BK + g*8);
    }
    __syncthreads();
    for (int ks = 0; ks < 2; ++ks) {
      bfrag8 a[4], b[4];
      for (int i = 0; i < 4; ++i) a[i] = *(const bfrag8*)(&As[wm*64 + i*16 + lm][ks*32 + q*8]);
      for (int j = 0; j < 4; ++j) b[j] = *(const bfrag8*)(&Bs[wn*64 + j*16 + lm][ks*32 + q*8]);
      for (int i = 0; i < 4; ++i)
        for (int j = 0; j < 4; ++j)
          acc[i][j] = __builtin_amdgcn_mfma_f32_16x16x32_bf16(a[i], b[j], acc[i][j], 0, 0, 0);
    }
    __syncthreads();
  }
  for (int j = 0; j < 4; ++j) {
    int o = col0 + wn*64 + j*16 + lm;
    float bi = bias[o];
    for (int i = 0; i < 4; ++i) {
      int prow = row0 + wm*64 + i*16 + q*4;
      for (int r = 0; r < 4; ++r)
        Cout[(size_t)(prow + r)*768 + o] = f2b(acc[i][j][r] + bi);
    }
  }
}

// ---------------- per-pixel 2x2 cross-view attention ----------------
__global__ void k_attn(const unsigned short* __restrict__ qkvt,  // [2][16384][768]
                       unsigned short* __restrict__ outt) {      // [2][16384][256]
  int w = threadIdx.x >> 6, lane = threadIdx.x & 63;   // lane = hd index
  int task = blockIdx.x * 4 + w;                       // 65536 tasks
  int p = task >> 2, h = task & 3;
  const unsigned short* b0 = qkvt + (size_t)p * 768 + h * 64 + lane;
  const unsigned short* b1 = b0 + (size_t)HW * 768;
  float q0 = b2f(b0[0]), k0 = b2f(b0[256]), v0 = b2f(b0[512]);
  float q1 = b2f(b1[0]), k1 = b2f(b1[256]), v1 = b2f(b1[512]);
  float s00 = q0*k0, s01 = q0*k1, s10 = q1*k0, s11 = q1*k1;
  for (int off = 32; off; off >>= 1) {
    s00 += __shfl_xor(s00, off);
    s01 += __shfl_xor(s01, off);
    s10 += __shfl_xor(s10, off);
    s11 += __shfl_xor(s11, off);
  }
  s00 *= 0.125f; s01 *= 0.125f; s10 *= 0.125f; s11 *= 0.125f;
  float m0 = fmaxf(s00, s01), m1 = fmaxf(s10, s11);
  float e00 = __expf(s00 - m0), e01 = __expf(s01 - m0);
  float e10 = __expf(s10 - m1), e11 = __expf(s11 - m1);
  float r0 = 1.f / (e00 + e01), r1 = 1.f / (e10 + e11);
  float o0 = (e00*v0 + e01*v1) * r0;
  float o1 = (e10*v0 + e11*v1) * r1;
  outt[(size_t)p * 256 + h*64 + lane] = f2b(o0);
  outt[(size_t)(HW + p) * 256 + h*64 + lane] = f2b(o1);
}

// ---------------- proj GEMM: D[o][pix] = wp[o][k] . outt[pix][k] + bp[o] + x, fp32 out ----------------
__global__ __launch_bounds__(256, 2) void k_gemm_proj(
    const unsigned short* __restrict__ A,   // wpb [256][256]
    const unsigned short* __restrict__ B,   // outt [32768][256]
    const float* __restrict__ bias,         // [256]
    const float* __restrict__ xp,           // x pair base [2][256][16384]
    float* __restrict__ out) {              // out pair base
  __shared__ unsigned short As[128][LDSP];
  __shared__ unsigned short Bs[128][LDSP];
  int col0 = blockIdx.x * 128;   // pixels (0..32767)
  int row0 = blockIdx.y * 128;   // o (0..255)
  int t = threadIdx.x;
  int w = t >> 6, lane = t & 63;
  int wm = w & 1, wn = w >> 1;
  int lm = lane & 15, q = lane >> 4;
  facc4 acc[4][4] = {};
  for (int kc = 0; kc < 4; ++kc) {
    for (int i = 0; i < 4; ++i) {
      int flat = i * 256 + t;
      int r = flat >> 3, g = flat & 7;
      *(us8*)(&As[r][g*8]) = *(const us8*)(A + (size_t)(row0 + r)*256 + kc*BK + g*8);
      *(us8*)(&Bs[r][g*8]) = *(const us8*)(B + (size_t)(col0 + r)*256 + kc*BK + g*8);
    }
    __syncthreads();
    for (int ks = 0; ks < 2; ++ks) {
      bfrag8 a[4], b[4];
      for (int i = 0; i < 4; ++i) a[i] = *(const bfrag8*)(&As[wm*64 + i*16 + lm][ks*32 + q*8]);
      for (int j = 0; j < 4; ++j) b[j] = *(const bfrag8*)(&Bs[wn*64 + j*16 + lm][ks*32 + q*8]);
      for (int i = 0; i < 4; ++i)
        for (int j = 0; j < 4; ++j)
          acc[i][j] = __builtin_amdgcn_mfma_f32_16x16x32_bf16(a[i], b[j], acc[i][j], 0, 0, 0);
    }
    __syncthreads();
  }
  for (int i = 0; i < 4; ++i) {
    for (int r = 0; r < 4; ++r) {
      int o = row0 + wm*64 + i*16 + q*4 + r;
      float bi = bias[o];
      for (int j = 0; j < 4; ++j) {
        int n = col0 + wn*64 + j*16 + lm;       // global pixel col in [0,32768)
        int v = n >> 14, p = n & (HW - 1);
        size_t gidx = (size_t)v * CCH * HW + (size_t)o * HW + p;
        out[gidx] = acc[i][j][r] + bi + xp[gidx];
      }
    }
  }
}

extern "C" void kernel_launch(void* const* d_in, const int* in_sizes, int n_in,
                              void* d_out, int out_size, void* d_ws, size_t ws_size,
                              hipStream_t stream) {
  const float* x     = (const float*)d_in[0];
  const float* gamma = (const float*)d_in[1];
  const float* beta  = (const float*)d_in[2];
  const float* wq    = (const float*)d_in[3];
  const float* bq    = (const float*)d_in[4];
  const float* wp    = (const float*)d_in[5];
  const float* bp    = (const float*)d_in[6];
  float* out = (float*)d_out;

  char* ws = (char*)d_ws;
  float* red   = (float*)ws;                    // 512 B (must be zeroed)
  float* stats = (float*)(ws + 512);            // 512 B
  unsigned short* wqb = (unsigned short*)(ws + 1024);            // 393216 B
  unsigned short* wpb = (unsigned short*)(ws + 1024 + 393216);   // 131072 B
  size_t off = 1024 + 393216 + 131072;
  unsigned short* xnt  = (unsigned short*)(ws + off); off += (size_t)2*HW*CCH*2;  // 16.8 MB
  unsigned short* qkvt = (unsigned short*)(ws + off); off += (size_t)2*HW*768*2;  // 50.3 MB
  unsigned short* outt = (unsigned short*)(ws + off);                              // 16.8 MB

  hipMemsetAsync(red, 0, 1024, stream);
  k_cast<<<1024, 256, 0, stream>>>(wq, wp, wqb, wpb);
  k_red<<<512, 256, 0, stream>>>(x, red);
  k_fin<<<1, 64, 0, stream>>>(red, stats);

  for (int pair = 0; pair < 4; ++pair) {
    const float* xp = x   + (size_t)pair * 2 * CCH * HW;
    float*       op = out + (size_t)pair * 2 * CCH * HW;
    k_norm_t<<<2048, 256, 0, stream>>>(xp, stats, gamma, beta, xnt, pair);
    k_gemm_qkv<<<dim3(256, 6), 256, 0, stream>>>(xnt, wqb, bq, qkvt);
    k_attn<<<16384, 256, 0, stream>>>(qkvt, outt);
    k_gemm_proj<<<dim3(256, 2), 256, 0, stream>>>(wpb, outt, bp, xp, op);
  }
}

// Round 2
// 440.289 us; speedup vs baseline: 1.1873x; 1.1873x over previous
//
#include <hip/hip_runtime.h>
#include <stdint.h>

#define HW 16384
#define CCH 256
#define NROWS 131072          // 4 pairs * 16384 px * 2 views (interleaved rows)
#define GROUP_ELEMS 524288    // 32 ch * 16384 px
#define BK 64
#define LDSP 72               // staging row stride (bf16): 144 B, 16B aligned
#define PADC 198              // attn tile row stride (bf16): word-stride 99 (odd -> banks spread)

typedef __attribute__((ext_vector_type(8))) short bfrag8;
typedef __attribute__((ext_vector_type(8))) unsigned short us8;
typedef __attribute__((ext_vector_type(4))) float facc4;

static __device__ __forceinline__ unsigned short f2b(float f) {
  union { float f; unsigned int u; } x; x.f = f;
  unsigned int r = x.u + 0x7FFFu + ((x.u >> 16) & 1u);
  return (unsigned short)(r >> 16);
}
static __device__ __forceinline__ float b2f(unsigned short h) {
  union { float f; unsigned int u; } x; x.u = ((unsigned int)h) << 16;
  return x.f;
}

// ---------------- GroupNorm stats ----------------
__global__ void k_red(const float* __restrict__ x, float* __restrict__ red) {
  int gg = blockIdx.x >> 3, sp = blockIdx.x & 7;   // 64 groups x 8 splits
  const float4* p = (const float4*)(x + (size_t)gg * GROUP_ELEMS + (size_t)sp * 65536);
  float s = 0.f, ss = 0.f;
  for (int i = 0; i < 64; ++i) {
    float4 v = p[i * 256 + threadIdx.x];
    s  += v.x + v.y + v.z + v.w;
    ss += v.x*v.x + v.y*v.y + v.z*v.z + v.w*v.w;
  }
  for (int off = 32; off; off >>= 1) { s += __shfl_xor(s, off); ss += __shfl_xor(ss, off); }
  __shared__ float ls[4], lss[4];
  int w = threadIdx.x >> 6;
  if ((threadIdx.x & 63) == 0) { ls[w] = s; lss[w] = ss; }
  __syncthreads();
  if (threadIdx.x == 0) {
    float S = ls[0]+ls[1]+ls[2]+ls[3], SS = lss[0]+lss[1]+lss[2]+lss[3];
    atomicAdd(&red[gg*2], S); atomicAdd(&red[gg*2+1], SS);
  }
}

__global__ void k_fin(const float* __restrict__ red, float* __restrict__ stats) {
  int g = threadIdx.x;
  float s = red[g*2], ss = red[g*2+1];
  float mean = s / (float)GROUP_ELEMS;
  float var = ss / (float)GROUP_ELEMS - mean*mean;
  stats[g*2] = mean;
  stats[g*2+1] = rsqrtf(var + 1e-5f);
}

// ------- weight cast; w_qkv reordered head-major: o' = h*192 + part*64 + d -------
__global__ void k_cast(const float* __restrict__ wq, const float* __restrict__ wp,
                       unsigned short* __restrict__ wqb, unsigned short* __restrict__ wpb) {
  int i = blockIdx.x * 256 + threadIdx.x;   // grid 1024 -> 262144 = 196608 + 65536 exactly
  if (i < 768*256) {
    int op = i >> 8, k = i & 255;
    int h = op / 192, cl = op % 192;
    int part = cl >> 6, d = cl & 63;
    int o = part*256 + h*64 + d;
    wqb[i] = f2b(wq[o*256 + k]);
  } else {
    int j = i - 768*256;
    wpb[j] = f2b(wp[j]);
  }
}

// ---- norm + transpose: x[bv][c][p] fp32 -> xnt[row=pair*32768 + p*2 + v][c] bf16 ----
__global__ void k_norm_t(const float* __restrict__ x, const float* __restrict__ stats,
                         const float* __restrict__ gamma, const float* __restrict__ beta,
                         unsigned short* __restrict__ xnt) {
  __shared__ float tile[64][65];
  int bx = blockIdx.x;               // 8192 blocks: bv(8) x ptile(256) x ctile(4)
  int bv = bx >> 10;
  int rem = bx & 1023;
  int p0 = (rem >> 2) * 64, c0 = (rem & 3) * 64;
  int pair = bv >> 1, v = bv & 1;
  int t = threadIdx.x;
  int p_off = t & 63, c4 = t >> 6;
  const float* xsrc = x + (size_t)bv * CCH * HW;
  for (int cc = 0; cc < 16; ++cc) {
    int c_loc = c4 * 16 + cc;
    int c = c0 + c_loc;
    float val = xsrc[(size_t)c * HW + p0 + p_off];
    int g = bv * 8 + (c >> 5);
    float xn = (val - stats[g*2]) * stats[g*2+1] * gamma[c] + beta[c];
    tile[p_off][c_loc] = xn;
  }
  __syncthreads();
  for (int it = 0; it < 8; ++it) {
    int u = it * 256 + t;
    int p = u >> 5, c2 = u & 31;
    unsigned int pk = (unsigned int)f2b(tile[p][c2*2]) | ((unsigned int)f2b(tile[p][c2*2+1]) << 16);
    size_t row = (size_t)pair * 32768 + (size_t)(p0 + p) * 2 + v;
    *(unsigned int*)(xnt + row * 256 + c0 + c2*2) = pk;
  }
}

// ------- fused QKV GEMM + cross-view attention -------
// A = xnt [131072][256] (row = gp*2+v), B = wqb reordered [768][256], tile 128x192 (one head).
// Epilogue: bias -> LDS tile [128][192] (q|k|v) -> per-pixel 2x2 softmax -> PV ->
// attn_out[bv*16384+p][c = h*64+d] bf16 (view-major for proj).
__global__ __launch_bounds__(256, 2) void k_qkv_attn(
    const unsigned short* __restrict__ A,
    const unsigned short* __restrict__ B,
    const float* __restrict__ bq,
    unsigned short* __restrict__ attn_out) {
  __shared__ __align__(16) unsigned short smem[128 * PADC];  // union: staging | attn tile
  __shared__ float sW[256];
  unsigned short* As = smem;                 // [128][LDSP]
  unsigned short* Bs = smem + 128 * LDSP;    // [192][LDSP]
  int h = blockIdx.x;                        // head (fast dim -> A-tile L2 reuse)
  int row0 = blockIdx.y * 128;
  int t = threadIdx.x;
  int w = t >> 6, lane = t & 63;
  int wm = w & 1, wn = w >> 1;
  int lm = lane & 15, q = lane >> 4;
  facc4 acc[4][6] = {};
  const unsigned short* Bh = B + (size_t)h * 192 * 256;
  for (int kc = 0; kc < 4; ++kc) {
    for (int i = 0; i < 4; ++i) {
      int flat = i * 256 + t;
      int r = flat >> 3, g = flat & 7;
      *(us8*)(&As[r*LDSP + g*8]) = *(const us8*)(A + (size_t)(row0 + r)*256 + kc*BK + g*8);
    }
    for (int i = 0; i < 6; ++i) {
      int flat = i * 256 + t;
      int r = flat >> 3, g = flat & 7;
      *(us8*)(&Bs[r*LDSP + g*8]) = *(const us8*)(Bh + (size_t)r*256 + kc*BK + g*8);
    }
    __syncthreads();
    for (int ks = 0; ks < 2; ++ks) {
      bfrag8 a[4], b[6];
      for (int i = 0; i < 4; ++i) a[i] = *(const bfrag8*)(&As[(wm*64 + i*16 + lm)*LDSP + ks*32 + q*8]);
      for (int j = 0; j < 6; ++j) b[j] = *(const bfrag8*)(&Bs[(wn*96 + j*16 + lm)*LDSP + ks*32 + q*8]);
      for (int i = 0; i < 4; ++i)
        for (int j = 0; j < 6; ++j)
          acc[i][j] = __builtin_amdgcn_mfma_f32_16x16x32_bf16(a[i], b[j], acc[i][j], 0, 0, 0);
    }
    __syncthreads();
  }
  // epilogue 1: bias + bf16 tile into LDS (overwrites staging; safe after final barrier)
  unsigned short* sT = smem;  // [128][PADC], cols 0-63=q, 64-127=k, 128-191=v
  for (int j = 0; j < 6; ++j) {
    int cl = wn*96 + j*16 + lm;
    int part = cl >> 6, d = cl & 63;
    float bi = bq[part*256 + h*64 + d];
    for (int i = 0; i < 4; ++i) {
      int rl = wm*64 + i*16 + q*4;
      for (int r = 0; r < 4; ++r)
        sT[(rl + r)*PADC + cl] = f2b(acc[i][j][r] + bi);
    }
  }
  __syncthreads();
  // epilogue 2: scores + softmax weights. t = px*4 + s, s = qv*2+kv.
  {
    int px = t >> 2, s = t & 3;
    int qv = s >> 1, kv = s & 1;
    const unsigned short* qrow = sT + (2*px + qv)*PADC;
    const unsigned short* krow = sT + (2*px + kv)*PADC + 64;
    float dot = 0.f;
    for (int d = 0; d < 64; ++d) dot += b2f(qrow[d]) * b2f(krow[d]);
    dot *= 0.125f;
    float other = __shfl_xor(dot, 1);
    float m = fmaxf(dot, other);
    float e = __expf(dot - m), eo = __expf(other - m);
    sW[px*4 + s] = e / (e + eo);
  }
  __syncthreads();
  // epilogue 3: O = w0*v0 + w1*v1, coalesced bf16 store (view-major layout)
  int gp0 = blockIdx.y * 64;   // global pixel base (across pairs)
  for (int it = 0; it < 32; ++it) {
    int u = it * 256 + t;
    int d = u & 63, vv = (u >> 6) & 1, px = u >> 7;
    float v0 = b2f(sT[(2*px)*PADC + 128 + d]);
    float v1 = b2f(sT[(2*px + 1)*PADC + 128 + d]);
    float o = sW[px*4 + vv*2] * v0 + sW[px*4 + vv*2 + 1] * v1;
    int g = gp0 + px;
    int pair = g >> 14, p = g & 16383;
    attn_out[((size_t)(pair*2 + vv) * 16384 + p) * 256 + h*64 + d] = f2b(o);
  }
}

// ---- proj GEMM: D[o][n] = wp[o][k] . attn_out[n][k] + bp[o] + x, fp32 out, batched ----
__global__ __launch_bounds__(256, 2) void k_gemm_proj(
    const unsigned short* __restrict__ A,   // wpb [256][256]
    const unsigned short* __restrict__ B,   // attn_out [131072][256]
    const float* __restrict__ bias,
    const float* __restrict__ x,
    float* __restrict__ out) {
  __shared__ unsigned short As[128][LDSP];
  __shared__ unsigned short Bs[128][LDSP];
  int col0 = blockIdx.x * 128;   // n in [0,131072)
  int row0 = blockIdx.y * 128;   // o in [0,256)
  int t = threadIdx.x;
  int w = t >> 6, lane = t & 63;
  int wm = w & 1, wn = w >> 1;
  int lm = lane & 15, q = lane >> 4;
  facc4 acc[4][4] = {};
  for (int kc = 0; kc < 4; ++kc) {
    for (int i = 0; i < 4; ++i) {
      int flat = i * 256 + t;
      int r = flat >> 3, g = flat & 7;
      *(us8*)(&As[r][g*8]) = *(const us8*)(A + (size_t)(row0 + r)*256 + kc*BK + g*8);
      *(us8*)(&Bs[r][g*8]) = *(const us8*)(B + (size_t)(col0 + r)*256 + kc*BK + g*8);
    }
    __syncthreads();
    for (int ks = 0; ks < 2; ++ks) {
      bfrag8 a[4], b[4];
      for (int i = 0; i < 4; ++i) a[i] = *(const bfrag8*)(&As[wm*64 + i*16 + lm][ks*32 + q*8]);
      for (int j = 0; j < 4; ++j) b[j] = *(const bfrag8*)(&Bs[wn*64 + j*16 + lm][ks*32 + q*8]);
      for (int i = 0; i < 4; ++i)
        for (int j = 0; j < 4; ++j)
          acc[i][j] = __builtin_amdgcn_mfma_f32_16x16x32_bf16(a[i], b[j], acc[i][j], 0, 0, 0);
    }
    __syncthreads();
  }
  for (int i = 0; i < 4; ++i) {
    for (int r = 0; r < 4; ++r) {
      int o = row0 + wm*64 + i*16 + q*4 + r;
      float bi = bias[o];
      for (int j = 0; j < 4; ++j) {
        int n = col0 + wn*64 + j*16 + lm;
        int bv = n >> 14, p = n & 16383;
        size_t gidx = ((size_t)bv * 256 + o) * 16384 + p;
        out[gidx] = acc[i][j][r] + bi + x[gidx];
      }
    }
  }
}

extern "C" void kernel_launch(void* const* d_in, const int* in_sizes, int n_in,
                              void* d_out, int out_size, void* d_ws, size_t ws_size,
                              hipStream_t stream) {
  const float* x     = (const float*)d_in[0];
  const float* gamma = (const float*)d_in[1];
  const float* beta  = (const float*)d_in[2];
  const float* wq    = (const float*)d_in[3];
  const float* bq    = (const float*)d_in[4];
  const float* wp    = (const float*)d_in[5];
  const float* bp    = (const float*)d_in[6];
  float* out = (float*)d_out;

  char* ws = (char*)d_ws;
  float* red   = (float*)ws;                    // 512 B (zeroed below)
  float* stats = (float*)(ws + 512);            // 512 B
  unsigned short* wqb = (unsigned short*)(ws + 1024);            // 393216 B (reordered)
  unsigned short* wpb = (unsigned short*)(ws + 1024 + 393216);   // 131072 B
  size_t off = 1024 + 393216 + 131072;
  unsigned short* xnt = (unsigned short*)(ws + off); off += (size_t)NROWS * 256 * 2;  // 67 MB
  unsigned short* att = (unsigned short*)(ws + off);                                   // 67 MB

  hipMemsetAsync(red, 0, 1024, stream);
  k_cast<<<1024, 256, 0, stream>>>(wq, wp, wqb, wpb);
  k_red<<<512, 256, 0, stream>>>(x, red);
  k_fin<<<1, 64, 0, stream>>>(red, stats);
  k_norm_t<<<8192, 256, 0, stream>>>(x, stats, gamma, beta, xnt);
  k_qkv_attn<<<dim3(4, 1024), 256, 0, stream>>>(xnt, wqb, bq, att);
  k_gemm_proj<<<dim3(1024, 2), 256, 0, stream>>>(wpb, att, bp, x, out);
}